// Round 1
// baseline (488.491 us; speedup 1.0000x reference)
//
#include <hip/hip_runtime.h>
#include <hip/hip_bf16.h>

#define NQ 2048
#define NB 512    // rows b
#define NX 256    // kernel centers per row
#define NR 1024   // grid resolution
#define KDE_EPS 1e-6f
#define SLOT_ELEMS (NB * NR)            // 524288 floats per bank slot
// C = log(256) + log(0.1) + log(sqrt(2*pi))
#define LOGC 4.1615308846901885f
#define NORM 0.015583685919813959f      // exp(-LOGC)

// ---------------------------------------------------------------------------
// Kernel 1: per-row min/max of samples and of y = f_sel(samples).
// Samples are never materialized beyond this.
// ---------------------------------------------------------------------------
__global__ __launch_bounds__(256) void row_stats(
    const float* __restrict__ inputs,   // (256, 512)
    const float* __restrict__ noise,    // (512, 2048)
    const int*   __restrict__ comp_idx, // (512, 2048)
    const int*   __restrict__ sel,      // (512,)
    float* __restrict__ stats)          // (4, 512): mns, mxs, mny, mxy
{
    const int b   = blockIdx.x;
    const int tid = threadIdx.x;
    const int selb = sel[b];

    float mns =  INFINITY, mxs = -INFINITY;
    float mny =  INFINITY, mxy = -INFINITY;

    for (int q = tid; q < NQ; q += 256) {
        const int   idx = comp_idx[b * NQ + q];
        const float nz  = noise[b * NQ + q];
        const float s   = inputs[idx * NB + b] + 0.1f * nz;
        mns = fminf(mns, s);
        mxs = fmaxf(mxs, s);
        const float ssafe = (fabsf(s) < KDE_EPS) ? KDE_EPS : s;
        float y;
        switch (selb) {
            case 0:  y = 2.0f * s; break;
            case 1:  y = s - 3.0f; break;
            case 2:  y = 1.0f / ssafe; break;
            case 3:  y = 0.8f * s + 5.0f; break;
            case 4:  y = 1.0f / (1.0f + __expf(-s)); break;
            default: y = fmaxf(s, 0.0f) + log1pf(__expf(-fabsf(s))); break; // softplus = logaddexp(s,0)
        }
        mny = fminf(mny, y);
        mxy = fmaxf(mxy, y);
    }

    // wave64 butterfly reduce
    #pragma unroll
    for (int off = 32; off > 0; off >>= 1) {
        mns = fminf(mns, __shfl_down(mns, off, 64));
        mxs = fmaxf(mxs, __shfl_down(mxs, off, 64));
        mny = fminf(mny, __shfl_down(mny, off, 64));
        mxy = fmaxf(mxy, __shfl_down(mxy, off, 64));
    }

    __shared__ float red[4][4];
    const int wave = tid >> 6;
    const int lane = tid & 63;
    if (lane == 0) {
        red[0][wave] = mns; red[1][wave] = mxs;
        red[2][wave] = mny; red[3][wave] = mxy;
    }
    __syncthreads();
    if (tid == 0) {
        float a = red[0][0], c = red[1][0], d = red[2][0], e = red[3][0];
        #pragma unroll
        for (int w = 1; w < 4; ++w) {
            a = fminf(a, red[0][w]);
            c = fmaxf(c, red[1][w]);
            d = fminf(d, red[2][w]);
            e = fmaxf(e, red[3][w]);
        }
        stats[0 * NB + b] = a;
        stats[1 * NB + b] = c;
        stats[2 * NB + b] = d;
        stats[3 * NB + b] = e;
    }
}

// ---------------------------------------------------------------------------
// Kernel 2: evaluate current (slot 0) and transformed (slot 1) on the grids.
// One block per (b, chunk-of-256 r). x-column cached in LDS (pre-scaled by 10).
// ---------------------------------------------------------------------------
__global__ __launch_bounds__(256) void grid_eval(
    const float* __restrict__ inputs,    // (256, 512)
    const int*   __restrict__ sel,       // (512,)
    const int*   __restrict__ slot_idx_p,
    const float* __restrict__ stats,     // (4, 512)
    float* __restrict__ out)             // (128, 512, 1024)
{
    const int b     = blockIdx.x;   // 512
    const int chunk = blockIdx.y;   // 4
    const int tid   = threadIdx.x;  // 256

    __shared__ float xs10[NX];
    xs10[tid] = inputs[tid * NB + b] * 10.0f;
    __syncthreads();

    const int   r  = chunk * 256 + tid;
    const float rr = (float)r / 1023.0f;

    const float mns = stats[0 * NB + b];
    const float mxs = stats[1 * NB + b];
    const float mny = stats[2 * NB + b];
    const float mxy = stats[3 * NB + b];

    float t0 = mns + (mxs - mns) * rr;
    if (t0 == 0.0f) t0 = 1e-7f;
    float t1 = mny + (mxy - mny) * rr;
    if (t1 == 0.0f) t1 = 1e-7f;

    const int selb = sel[b];
    const float yc01 = fminf(fmaxf(t1, KDE_EPS), 1.0f - KDE_EPS);
    const float ycp  = fmaxf(t1, KDE_EPS);

    float xi, ld;
    switch (selb) {
        case 0:  xi = 0.5f * t1;            ld = -0.6931471805599453f; break;
        case 1:  xi = t1 + 3.0f;            ld = 0.0f;                 break;
        case 2:  xi = 1.0f / t1;            ld = -2.0f * logf(fabsf(t1)); break;
        case 3:  xi = (t1 - 5.0f) * 1.25f;  ld = 0.22314355131420976f; break;
        case 4:  xi = logf(yc01) - log1pf(-yc01);
                 ld = -logf(yc01) - log1pf(-yc01);                     break;
        default: { const float em = expm1f(ycp);
                   xi = logf(em);
                   ld = ycp - xi; }                                     break;
    }

    const float t010 = t0 * 10.0f;
    const float xi10 = xi * 10.0f;

    float acc0 = 0.0f, acc1 = 0.0f;
    #pragma unroll 8
    for (int j = 0; j < NX; ++j) {
        const float xv = xs10[j];
        const float z0 = t010 - xv;
        const float z1 = xi10 - xv;
        acc0 += __expf(-0.5f * z0 * z0);
        acc1 += __expf(-0.5f * z1 * z1);
    }

    const float current     = acc0 * NORM;
    // log-space recombine so acc1==0 with huge ld stays 0 (matches reference),
    // never 0 * inf = NaN.
    const float transformed = __expf(__logf(acc1) + ld - LOGC);

    const int slot_idx = *slot_idx_p;
    const size_t o = (size_t)b * NR + r;
    if (slot_idx != 0) out[o] = current;
    if (slot_idx != 1) out[SLOT_ELEMS + o] = transformed;
}

// ---------------------------------------------------------------------------
// Kernel 3: bank permute-copy. out[k]=bank[k] (k>=2, k!=slot), out[slot]=bank[0].
// float4, fully coalesced.
// ---------------------------------------------------------------------------
__global__ __launch_bounds__(256) void copy_bank(
    const float4* __restrict__ bank,
    const int*    __restrict__ slot_idx_p,
    float4* __restrict__ out)
{
    const int PER_SLOT_V4 = SLOT_ELEMS / 4; // 131072 = 2^17
    const int slot_idx = *slot_idx_p;
    const size_t i = (size_t)blockIdx.x * blockDim.x + threadIdx.x;
    const int slot = (int)(i >> 17);
    const size_t pos = i & (size_t)(PER_SLOT_V4 - 1);
    if (slot == slot_idx) {
        out[i] = bank[pos];          // prev = original bank[0]
    } else if (slot >= 2) {
        out[i] = bank[i];
    }
    // slots 0/1 (when != slot_idx) are written by grid_eval
}

extern "C" void kernel_launch(void* const* d_in, const int* in_sizes, int n_in,
                              void* d_out, int out_size, void* d_ws, size_t ws_size,
                              hipStream_t stream) {
    const float* inputs   = (const float*)d_in[0]; // (256,512)
    const float* bank     = (const float*)d_in[1]; // (128,512,1024)
    const float* noise    = (const float*)d_in[2]; // (512,2048)
    const int*   comp_idx = (const int*)d_in[3];   // (512,2048)
    const int*   sel      = (const int*)d_in[4];   // (512,)
    const int*   slotp    = (const int*)d_in[5];   // scalar
    float* out   = (float*)d_out;
    float* stats = (float*)d_ws;                   // 4*512 floats

    row_stats<<<NB, 256, 0, stream>>>(inputs, noise, comp_idx, sel, stats);

    dim3 g2(NB, NR / 256);
    grid_eval<<<g2, 256, 0, stream>>>(inputs, sel, slotp, stats, out);

    const int total_v4 = 128 * (SLOT_ELEMS / 4);
    copy_bank<<<total_v4 / 256, 256, 0, stream>>>((const float4*)bank, slotp, (float4*)out);
}